// Round 5
// baseline (152.055 us; speedup 1.0000x reference)
//
#include <hip/hip_runtime.h>
#include <cstdint>
#include <cstddef>

// Problem constants (from reference): N=16384, D=256.
#define NV 16384
#define DD 256
#define BLK 1024
#define TPB 256            // k_mis threads (4 waves)
#define VPT (BLK / TPB)    // 4 vertices per thread per block
#define PCAP 7
#define HROW 24   // u16 slots per vertex in hi_g: [0]=count, [1..23]=higher nbrs

// ---------------------------------------------------------------------------
// K_prep (parallel, one pass over nbr): per vertex v emit
//  - pend_g[v] (uint4): in-1024-block lower neighbors as u16 offsets
//      x = count | e0<<16 ; y = e1|e2<<16 ; z = e3|e4<<16 ; w = e5|e6<<16
//  - hi_g[v*HROW..]: [count, up to 23 higher-neighbor vertex ids] (u16)
// ---------------------------------------------------------------------------
__global__ __launch_bounds__(256)
void k_prep(const int* __restrict__ nbr, const int* __restrict__ deg,
            int maxdeg, int n, uint4* __restrict__ pend_g,
            unsigned short* __restrict__ hi_g)
{
    int v = blockIdx.x * 256 + threadIdx.x;
    if (v >= n) return;
    const int b  = v & ~(BLK - 1);
    const int dv = deg[v];
    const int* __restrict__ row = nbr + (size_t)v * (size_t)maxdeg;
    unsigned short* __restrict__ hrow = hi_g + (size_t)v * HROW;
    unsigned w0 = 0, w1 = 0, w2 = 0, w3 = 0;
    int cnt = 0, hic = 0;
    for (int k = 0; k < dv; ++k) {
        int j = row[k];
        if (j > v) {
            if (hic < HROW - 1) hrow[1 + hic] = (unsigned short)j;
            ++hic;
        } else if (j >= b) {
            unsigned val = (unsigned)(j - b);
            switch (cnt) {
                case 0: w0 |= val << 16; break;
                case 1: w1 |= val;       break;
                case 2: w1 |= val << 16; break;
                case 3: w2 |= val;       break;
                case 4: w2 |= val << 16; break;
                case 5: w3 |= val;       break;
                case 6: w3 |= val << 16; break;
                default: break;
            }
            ++cnt;
        }
    }
    hrow[0] = (unsigned short)hic;
    w0 |= (unsigned)(cnt > 0xffff ? 0xffff : cnt);
    uint4 p; p.x = w0; p.y = w1; p.z = w2; p.w = w3;
    pend_g[v] = p;
}

// ---------------------------------------------------------------------------
// K_mis: lexicographic greedy MIS, single WG of 256 threads (4 waves).
// Each thread owns VPT=4 vertices of the current 1024-block: v = b + t + 256*i.
// st: 0=unknown, 1=head, 2=nonhead (monotone -> LDS races benign).
// Heads push st=2 to higher neighbors from REGISTER-resident hi lists.
// 3 decision passes per barrier collapse ~3 dependency levels per round.
// ---------------------------------------------------------------------------
__global__ __launch_bounds__(TPB)
void k_mis(const int* __restrict__ nbr, const int* __restrict__ deg,
           int maxdeg, int n,
           const uint4* __restrict__ pend_g, const unsigned short* __restrict__ hi_g,
           int* __restrict__ headlist, float* __restrict__ out_tail)
{
    __shared__ __align__(16) unsigned char st[NV];
    __shared__ int s_ws[TPB / 64];
    __shared__ int F[3];
    const int t    = threadIdx.x;
    const int lane = t & 63;
    const int wid  = t >> 6;

    #pragma unroll
    for (int i = 0; i < NV / 16 / TPB; ++i)
        ((uint4*)st)[t + TPB * i] = make_uint4(0u, 0u, 0u, 0u);
    if (t < 3) F[t] = 0;
    __syncthreads();

    // register state per owned vertex, double-buffered across blocks
    uint4 pv[VPT], a0[VPT], a1[VPT], a2[VPT];
    int   dv[VPT];
    #pragma unroll
    for (int i = 0; i < VPT; ++i) {
        int v = t + TPB * i;
        pv[i] = make_uint4(0,0,0,0); a0[i] = a1[i] = a2[i] = pv[i]; dv[i] = 0;
        if (v < n) {
            pv[i] = pend_g[v];
            const uint4* hp = (const uint4*)(hi_g + (size_t)v * HROW);
            a0[i] = hp[0]; a1[i] = hp[1]; a2[i] = hp[2];
            dv[i] = deg[v];
        }
    }
    int r = 0;

    for (int b = 0; b < n; b += BLK) {
        // prefetch next block into shadow regs
        uint4 qv[VPT], b0[VPT], b1[VPT], b2[VPT];
        int   dn[VPT];
        #pragma unroll
        for (int i = 0; i < VPT; ++i) {
            int vn = b + BLK + t + TPB * i;
            qv[i] = make_uint4(0,0,0,0); b0[i] = b1[i] = b2[i] = qv[i]; dn[i] = 0;
            if (vn < n) {
                qv[i] = pend_g[vn];
                const uint4* hp = (const uint4*)(hi_g + (size_t)vn * HROW);
                b0[i] = hp[0]; b1[i] = hp[1]; b2[i] = hp[2];
                dn[i] = deg[vn];
            }
        }

        int my[VPT];
        #pragma unroll
        for (int i = 0; i < VPT; ++i) my[i] = (b + t + TPB * i < n) ? 0 : 2;

        for (;; ++r) {
            if (t == 0) F[(r + 1) % 3] = 0;
            #pragma unroll
            for (int pass = 0; pass < 3; ++pass) {
                #pragma unroll
                for (int i = 0; i < VPT; ++i) {
                    if (my[i] != 0) continue;
                    const int v = b + t + TPB * i;
                    if (st[v] != 0) { my[i] = 2; continue; }
                    const int np = pv[i].x & 0xffff;
                    bool anyH = false; int undec = 0;
                    if (np <= PCAP) {
                        if (np > 0) { int s = st[b + (pv[i].x >> 16)];      anyH |= (s == 1); undec += (s == 0); }
                        if (np > 1) { int s = st[b + (pv[i].y & 0xffff)];   anyH |= (s == 1); undec += (s == 0); }
                        if (np > 2) { int s = st[b + (pv[i].y >> 16)];      anyH |= (s == 1); undec += (s == 0); }
                        if (np > 3) { int s = st[b + (pv[i].z & 0xffff)];   anyH |= (s == 1); undec += (s == 0); }
                        if (np > 4) { int s = st[b + (pv[i].z >> 16)];      anyH |= (s == 1); undec += (s == 0); }
                        if (np > 5) { int s = st[b + (pv[i].w & 0xffff)];   anyH |= (s == 1); undec += (s == 0); }
                        if (np > 6) { int s = st[b + (pv[i].w >> 16)];      anyH |= (s == 1); undec += (s == 0); }
                    } else {
                        const int* __restrict__ row = nbr + (size_t)v * (size_t)maxdeg;
                        for (int k = 0; k < dv[i]; ++k) {
                            int j = row[k];
                            if (j >= b && j < v) {
                                int s = st[j];
                                anyH |= (s == 1); undec += (s == 0);
                            }
                        }
                    }
                    if (anyH) { my[i] = 2; }
                    else if (undec == 0) {
                        my[i] = 1;
                        st[v] = 1;
                        const int hic = (int)(a0[i].x & 0xffff);
                        if (hic <= HROW - 1) {
                            #define PUSHE(word, sh, k) if ((k) < hic) st[((word) >> (sh)) & 0xffffu] = 2
                            PUSHE(a0[i].x,16, 0); PUSHE(a0[i].y, 0, 1); PUSHE(a0[i].y,16, 2);
                            PUSHE(a0[i].z, 0, 3); PUSHE(a0[i].z,16, 4); PUSHE(a0[i].w, 0, 5);
                            PUSHE(a0[i].w,16, 6);
                            PUSHE(a1[i].x, 0, 7); PUSHE(a1[i].x,16, 8); PUSHE(a1[i].y, 0, 9);
                            PUSHE(a1[i].y,16,10); PUSHE(a1[i].z, 0,11); PUSHE(a1[i].z,16,12);
                            PUSHE(a1[i].w, 0,13); PUSHE(a1[i].w,16,14);
                            PUSHE(a2[i].x, 0,15); PUSHE(a2[i].x,16,16); PUSHE(a2[i].y, 0,17);
                            PUSHE(a2[i].y,16,18); PUSHE(a2[i].z, 0,19); PUSHE(a2[i].z,16,20);
                            PUSHE(a2[i].w, 0,21); PUSHE(a2[i].w,16,22);
                            #undef PUSHE
                        } else {
                            const int* __restrict__ row = nbr + (size_t)v * (size_t)maxdeg;
                            for (int k = 0; k < dv[i]; ++k) {
                                int j = row[k];
                                if (j > v) st[j] = 2;
                            }
                        }
                    }
                }
            }
            bool und = (my[0] == 0) | (my[1] == 0) | (my[2] == 0) | (my[3] == 0);
            if (und) F[r % 3] = 1;
            __syncthreads();
            if (F[r % 3] == 0) { ++r; break; }
        }
        #pragma unroll
        for (int i = 0; i < VPT; ++i) {
            pv[i] = qv[i]; a0[i] = b0[i]; a1[i] = b1[i]; a2[i] = b2[i]; dv[i] = dn[i];
        }
    }

    // ---- epilogue: count heads, scan, emit headlist / head_mask / count ----
    // thread t owns bytes [64t, 64t+64)
    int cnt = 0;
    #pragma unroll
    for (int i = 0; i < 4; ++i) {
        uint4 q = ((const uint4*)st)[t * 4 + i];
        cnt += __popc(q.x & 0x01010101u) + __popc(q.y & 0x01010101u)
             + __popc(q.z & 0x01010101u) + __popc(q.w & 0x01010101u);
    }
    int c = cnt;
    #pragma unroll
    for (int off = 1; off < 64; off <<= 1) {
        int x = __shfl_up(c, off);
        if (lane >= off) c += x;
    }
    if (lane == 63) s_ws[wid] = c;
    __syncthreads();
    int wexcl = 0, tot = 0;
    #pragma unroll
    for (int w = 0; w < TPB / 64; ++w) {
        int s = s_ws[w];
        tot += s;
        if (w < wid) wexcl += s;
    }
    int excl = wexcl + (c - cnt);
    for (int i = 0; i < 64; ++i) {
        int v = t * 64 + i;
        if (st[v] == 1) { headlist[excl] = v; ++excl; }
    }
    for (int i = t; i < n; i += TPB)
        out_tail[i] = (float)(st[i] & 1);            // head_mask, coalesced
    if (t == 0) out_tail[n] = (float)tot;            // num_clusters
}

// ---------------------------------------------------------------------------
// K_owner: 16 lanes per vertex. owner[v] = v if head else min head neighbor.
// ---------------------------------------------------------------------------
__global__ __launch_bounds__(256)
void k_owner(const int* __restrict__ nbr, const int* __restrict__ deg,
             int maxdeg, int n,
             const float* __restrict__ hm, int* __restrict__ owner)
{
    int gid = blockIdx.x * 256 + threadIdx.x;
    int v = gid >> 4, l = gid & 15;
    if (v >= n) return;
    if (hm[v] != 0.0f) { if (l == 0) owner[v] = v; return; }
    const int* __restrict__ row = nbr + (size_t)v * (size_t)maxdeg;
    const int dv = deg[v];
    int mn = 0x7fffffff;
    for (int k = l; k < dv; k += 16) {
        int j = row[k];
        if (hm[j] != 0.0f) mn = min(mn, j);
    }
    #pragma unroll
    for (int off = 8; off; off >>= 1) mn = min(mn, __shfl_xor(mn, off, 16));
    if (l == 0) owner[v] = mn;
}

// ---------------------------------------------------------------------------
// K_avg: one 64-lane wave per output row. Waves [0,tot): cluster mean for
// headlist[w]. Waves [tot,n): zero-fill the row (replaces the memset).
// ---------------------------------------------------------------------------
__global__ __launch_bounds__(256)
void k_avg(const float* __restrict__ vert, const int* __restrict__ nbr,
           const int* __restrict__ deg, int maxdeg, int n,
           const int* __restrict__ headlist, const int* __restrict__ owner,
           const float* __restrict__ tail, float* __restrict__ out)
{
    const int w    = (blockIdx.x * 256 + threadIdx.x) >> 6;
    const int lane = threadIdx.x & 63;
    if (w >= n) return;
    const int tot  = (int)tail[n];
    if (w >= tot) {
        reinterpret_cast<float4*>(out + (size_t)w * DD)[lane] = make_float4(0.f, 0.f, 0.f, 0.f);
        return;
    }
    const int h = headlist[w];

    const int dh = deg[h];
    const int* __restrict__ row = nbr + (size_t)h * (size_t)maxdeg;

    float4 acc = reinterpret_cast<const float4*>(vert + (size_t)h * DD)[lane];
    int cnt = 1;

    for (int k0 = 0; k0 < dh; k0 += 64) {
        int k = k0 + lane;
        int j = (k < dh) ? row[k] : -1;
        bool mem = (j >= 0) && (owner[j] == h);
        unsigned long long m = __ballot(mem);
        cnt += __popcll(m);
        while (m) {
            int bit = __ffsll((long long)m) - 1;
            m &= (m - 1);
            int jj = __shfl(j, bit);
            float4 rr = reinterpret_cast<const float4*>(vert + (size_t)jj * DD)[lane];
            acc.x += rr.x; acc.y += rr.y; acc.z += rr.z; acc.w += rr.w;
        }
    }
    const float inv = 1.0f / (float)cnt;
    float4 res;
    res.x = acc.x * inv; res.y = acc.y * inv;
    res.z = acc.z * inv; res.w = acc.w * inv;
    reinterpret_cast<float4*>(out + (size_t)w * DD)[lane] = res;
}

// ---------------------------------------------------------------------------
extern "C" void kernel_launch(void* const* d_in, const int* in_sizes, int n_in,
                              void* d_out, int out_size, void* d_ws, size_t ws_size,
                              hipStream_t stream)
{
    const float* vert = (const float*)d_in[0];
    const int*   nbr  = (const int*)d_in[1];
    const int*   deg  = (const int*)d_in[2];

    const int n      = in_sizes[2];            // 16384
    const int maxdeg = in_sizes[1] / n;
    const int d      = in_sizes[0] / n;        // 256

    int*   owner    = (int*)d_ws;                                  // n ints
    int*   headlist = owner + n;                                   // n ints
    uint4* pend_g   = (uint4*)(headlist + n);                      // n uint4
    unsigned short* hi_g = (unsigned short*)(pend_g + n);          // n * HROW u16

    float* out      = (float*)d_out;
    float* out_tail = out + (size_t)n * (size_t)d;   // head_mask .. num_clusters

    hipLaunchKernelGGL(k_prep, dim3((n + 255) / 256), dim3(256), 0, stream,
                       nbr, deg, maxdeg, n, pend_g, hi_g);

    hipLaunchKernelGGL(k_mis, dim3(1), dim3(TPB), 0, stream,
                       nbr, deg, maxdeg, n, pend_g, hi_g, headlist, out_tail);

    hipLaunchKernelGGL(k_owner, dim3((n * 16 + 255) / 256), dim3(256), 0, stream,
                       nbr, deg, maxdeg, n, out_tail, owner);

    const int blocks = (n * 64 + 255) / 256;   // one wave per output row
    hipLaunchKernelGGL(k_avg, dim3(blocks), dim3(256), 0, stream,
                       vert, nbr, deg, maxdeg, n, headlist, owner, out_tail, out);
}